// Round 4
// baseline (956.189 us; speedup 1.0000x reference)
//
#include <hip/hip_runtime.h>
#include <stdint.h>

#define NVERT 200000
#define NTET  1000000
#define NE2   3200000          // capacity for crossing-edge instances (E=3.0M, sigma~1.2k)
#define NG 1000

#define SCAN_T 256
#define SCAN_E 16
#define SCAN_EPB (SCAN_T*SCAN_E)   // 4096

__constant__ int c_tri[16][6] = {
  {-1,-1,-1,-1,-1,-1},{1,0,2,-1,-1,-1},{4,0,3,-1,-1,-1},{1,4,2,1,3,4},
  {3,1,5,-1,-1,-1},{2,3,0,2,5,3},{1,4,0,1,5,4},{4,2,5,-1,-1,-1},
  {4,5,2,-1,-1,-1},{4,1,0,4,5,1},{3,2,0,3,5,2},{1,3,5,-1,-1,-1},
  {4,1,2,4,3,1},{3,0,4,-1,-1,-1},{2,0,1,-1,-1,-1},{-1,-1,-1,-1,-1,-1}};
__constant__ int c_ntri[16] = {0,1,1,2,1,2,2,1,1,2,2,1,2,1,1,0};
__constant__ int c_e0[6] = {0,0,0,1,1,2};
__constant__ int c_e1[6] = {1,2,3,2,3,3};

__global__ void k_zero2(uint32_t* __restrict__ a, uint32_t* __restrict__ b, int n){
  int i = blockIdx.x*blockDim.x + threadIdx.x;
  if (i < n){ a[i] = 0u; b[i] = 0u; }
}

// sdf = sign*|abs|, occ = sdf > 0
__global__ void k_sdf(const float* __restrict__ ssign, const float* __restrict__ sabs,
                      float* __restrict__ sdf, uint8_t* __restrict__ occ){
  int i = blockIdx.x*blockDim.x + threadIdx.x;
  if (i >= NVERT) return;
  float s = ssign[i] * fabsf(sabs[i]);
  sdf[i] = s;
  occ[i] = (s > 0.0f) ? 1 : 0;
}

// per-tet: tetindex, one/two flags, bucket counts for CROSSING edges only
__global__ void k_tet(const int* __restrict__ idx, const uint8_t* __restrict__ occ,
                      uint8_t* __restrict__ tetidx, uint32_t* __restrict__ oneA,
                      uint32_t* __restrict__ twoA, uint32_t* __restrict__ bcnt){
  int t = blockIdx.x*blockDim.x + threadIdx.x;
  if (t >= NTET) return;
  int v[4];
  #pragma unroll
  for (int j = 0; j < 4; ++j) v[j] = idx[t*4+j];
  int ti = 0;
  #pragma unroll
  for (int j = 0; j < 4; ++j) ti |= (occ[v[j]] ? 1 : 0) << j;
  tetidx[t] = (uint8_t)ti;
  int nt = c_ntri[ti];
  oneA[t] = (nt == 1) ? 1u : 0u;
  twoA[t] = (nt == 2) ? 1u : 0u;
  if (nt == 0) return;
  #pragma unroll
  for (int e = 0; e < 6; ++e){
    int o0 = (ti >> c_e0[e]) & 1, o1 = (ti >> c_e1[e]) & 1;
    if (o0 == o1) continue;               // only crossing edges enter the pipeline
    int a = v[c_e0[e]], b = v[c_e1[e]];
    if (a > b){ int tmp = a; a = b; b = tmp; }
    atomicAdd((unsigned int*)&bcnt[a], 1u);
  }
}

// ---- generic in-place inclusive scan over u32 ----
__global__ void k_scan_block(uint32_t* __restrict__ d, uint32_t* __restrict__ part, int L){
  int tid = threadIdx.x;
  int base = blockIdx.x*SCAN_EPB + tid*SCAN_E;
  uint32_t v[SCAN_E];
  #pragma unroll
  for (int j = 0; j < SCAN_E; ++j){
    int i = base + j;
    v[j] = (i < L) ? d[i] : 0u;
  }
  #pragma unroll
  for (int j = 1; j < SCAN_E; ++j) v[j] += v[j-1];
  __shared__ uint32_t s[SCAN_T];
  s[tid] = v[SCAN_E-1];
  __syncthreads();
  for (int o = 1; o < SCAN_T; o <<= 1){
    uint32_t x = (tid >= o) ? s[tid-o] : 0u;
    __syncthreads();
    s[tid] += x;
    __syncthreads();
  }
  uint32_t off = s[tid] - v[SCAN_E-1];
  #pragma unroll
  for (int j = 0; j < SCAN_E; ++j){
    int i = base + j;
    if (i < L) d[i] = v[j] + off;
  }
  if (tid == SCAN_T-1 && part) part[blockIdx.x] = s[SCAN_T-1];
}

__global__ void k_scan_part(uint32_t* __restrict__ part, int n){
  int tid = threadIdx.x;
  int per = (n + SCAN_T - 1)/SCAN_T;
  int st = tid*per, en = st + per; if (en > n) en = n;
  uint32_t sum = 0;
  for (int i = st; i < en; ++i) sum += part[i];
  __shared__ uint32_t s[SCAN_T];
  s[tid] = sum;
  __syncthreads();
  for (int o = 1; o < SCAN_T; o <<= 1){
    uint32_t x = (tid >= o) ? s[tid-o] : 0u;
    __syncthreads();
    s[tid] += x;
    __syncthreads();
  }
  uint32_t off = s[tid] - sum;
  uint32_t run = off;
  for (int i = st; i < en; ++i){ run += part[i]; part[i] = run; }
}

__global__ void k_scan_add(uint32_t* __restrict__ d, const uint32_t* __restrict__ part, int L){
  int blk = blockIdx.x;
  if (blk == 0) return;
  uint32_t off = part[blk-1];
  int base = blk*SCAN_EPB;
  #pragma unroll
  for (int j = 0; j < SCAN_E; ++j){
    int i = base + j*SCAN_T + threadIdx.x;
    if (i < L) d[i] += off;
  }
}

// scatter crossing-edge b-values (u32) into per-min-vertex buckets
__global__ void k_scatter(const int* __restrict__ idx, const uint8_t* __restrict__ tetidx,
                          const uint32_t* __restrict__ bincl, uint32_t* __restrict__ fill,
                          uint32_t* __restrict__ skey){
  int t = blockIdx.x*blockDim.x + threadIdx.x;
  if (t >= NTET) return;
  int ti = tetidx[t];
  if (c_ntri[ti] == 0) return;
  int v[4];
  #pragma unroll
  for (int j = 0; j < 4; ++j) v[j] = idx[t*4+j];
  #pragma unroll
  for (int e = 0; e < 6; ++e){
    int o0 = (ti >> c_e0[e]) & 1, o1 = (ti >> c_e1[e]) & 1;
    if (o0 == o1) continue;
    int a = v[c_e0[e]], b = v[c_e1[e]];
    if (a > b){ int tmp = a; a = b; b = tmp; }
    uint32_t base = (a > 0) ? bincl[a-1] : 0u;
    uint32_t p = base + atomicAdd((unsigned int*)&fill[a], 1u);
    if (p < NE2) skey[p] = (uint32_t)b;
  }
}

// persistent-wave per-bucket rank sort (registers + shuffle), fused head-flag output.
// Stable tie-break by original index; head = first instance of its b-value.
__global__ void k_bsort(uint32_t* __restrict__ skey, const uint32_t* __restrict__ bincl,
                        uint32_t* __restrict__ maskA){
  int gid  = blockIdx.x*blockDim.x + threadIdx.x;
  int w    = gid >> 6;
  int lane = threadIdx.x & 63;
  int W    = (gridDim.x*blockDim.x) >> 6;
  for (int b = w; b < NVERT; b += W){
    uint32_t s0 = (b > 0) ? bincl[b-1] : 0u;
    uint32_t e0 = bincl[b];
    int n = (int)(e0 - s0);
    if (n <= 0) continue;
    if (n == 1){
      if (lane == 0) maskA[s0] = 1u;
      continue;
    }
    if (n <= 64){
      uint32_t ki = (lane < n) ? skey[s0+lane] : 0xFFFFFFFFu;
      int r = 0; bool dup = false;
      for (int j = 0; j < n; ++j){
        uint32_t kj = __shfl(ki, j, 64);
        bool tie = (kj == ki) && (j < lane);
        r += ((kj < ki) || tie) ? 1 : 0;
        dup |= tie;
      }
      if (lane < n){
        skey[s0 + r] = ki;
        maskA[s0 + r] = dup ? 0u : 1u;
      }
    } else if (n <= 128){
      uint32_t k0 = (lane < n)    ? skey[s0+lane]    : 0xFFFFFFFFu;
      uint32_t k1 = (64+lane < n) ? skey[s0+64+lane] : 0xFFFFFFFFu;
      int r0 = 0, r1 = 0; bool d0 = false, d1 = false;
      for (int j = 0; j < 64; ++j){           // elements [0,64) — indices < 64
        uint32_t kj = __shfl(k0, j, 64);
        bool t0 = (kj == k0) && (j < lane);
        r0 += ((kj < k0) || t0) ? 1 : 0;  d0 |= t0;
        bool t1 = (kj == k1);                 // j < 64 <= 64+lane always
        r1 += ((kj < k1) || t1) ? 1 : 0;  d1 |= t1;
      }
      for (int j = 0; j < 64; ++j){           // elements [64,128)
        if (64+j >= n) break;
        uint32_t kj = __shfl(k1, j, 64);
        r0 += (kj < k0) ? 1 : 0;              // 64+j > lane: ties not counted
        bool t1 = (kj == k1) && (j < lane);
        r1 += ((kj < k1) || t1) ? 1 : 0;  d1 |= t1;
      }
      if (lane < n)   { skey[s0 + r0] = k0; maskA[s0 + r0] = d0 ? 0u : 1u; }
      if (64+lane < n){ skey[s0 + r1] = k1; maskA[s0 + r1] = d1 ? 0u : 1u; }
    } else if (lane == 0){
      // pathological fallback (never expected at seed 0)
      for (int i = 1; i < n; ++i){
        uint32_t x = skey[s0+i];
        int j = i-1;
        while (j >= 0 && skey[s0+j] > x){ skey[s0+j+1] = skey[s0+j]; --j; }
        skey[s0+j+1] = x;
      }
      maskA[s0] = 1u;
      for (int i = 1; i < n; ++i) maskA[s0+i] = (skey[s0+i] != skey[s0+i-1]) ? 1u : 0u;
    }
  }
}

// bucket-parallel out_verts writer: head instances interpolate and store
__global__ void k_verts2(const uint32_t* __restrict__ skey, const uint32_t* __restrict__ maskI,
                         const uint32_t* __restrict__ bincl,
                         const float* __restrict__ verts, const float* __restrict__ deform,
                         const float* __restrict__ sdf, float* __restrict__ out){
  int gid  = blockIdx.x*blockDim.x + threadIdx.x;
  int w    = gid >> 6;
  int lane = threadIdx.x & 63;
  int W    = (gridDim.x*blockDim.x) >> 6;
  for (int a = w; a < NVERT; a += W){
    uint32_t s0 = (a > 0) ? bincl[a-1] : 0u;
    uint32_t e0 = bincl[a];
    int n = (int)(e0 - s0);
    if (n <= 0) continue;
    float sa = sdf[a];
    for (int base = 0; base < n; base += 64){
      int l = base + lane;
      if (l >= n) break;
      uint32_t bv = skey[s0+l];
      bool head = (l == 0) || (skey[s0+l-1] != bv);
      if (!head) continue;
      uint32_t vid = maskI[s0+l] - 1u;
      int b = (int)bv;
      float sb = sdf[b];
      float denom = sa - sb;
      float w0 = __fdiv_rn(-sb, denom);
      float w1 = __fdiv_rn(sa, denom);
      #pragma unroll
      for (int c = 0; c < 3; ++c){
        float pa = __fadd_rn(verts[a*3+c], __fmul_rn(0.0078125f, deform[a*3+c]));
        float pb = __fadd_rn(verts[b*3+c], __fmul_rn(0.0078125f, deform[b*3+c]));
        out[(size_t)vid*3 + c] = __fadd_rn(__fmul_rn(pa, w0), __fmul_rn(pb, w1));
      }
    }
  }
}

// faces + uv_idx: per tri edge, scan the (tiny, sorted, cache-resident) bucket for b
__global__ void k_faces(const int* __restrict__ idx, const uint8_t* __restrict__ tetidx,
                        const uint32_t* __restrict__ oneI, const uint32_t* __restrict__ twoI,
                        const uint32_t* __restrict__ maskI, const uint32_t* __restrict__ bincl,
                        const uint32_t* __restrict__ skey, float* __restrict__ out){
  int t = blockIdx.x*blockDim.x + threadIdx.x;
  if (t >= NTET) return;
  int ti = tetidx[t];
  int nt = c_ntri[ti];
  if (nt == 0) return;
  uint32_t nE      = (uint32_t)__builtin_amdgcn_readfirstlane((int)bincl[NVERT-1]);
  uint32_t nInterp = (uint32_t)__builtin_amdgcn_readfirstlane((int)maskI[nE-1]);
  uint32_t nOne    = (uint32_t)__builtin_amdgcn_readfirstlane((int)oneI[NTET-1]);
  uint32_t nTwo    = (uint32_t)__builtin_amdgcn_readfirstlane((int)twoI[NTET-1]);
  size_t facesOff = (size_t)3*nInterp;
  size_t nFaces = (size_t)nOne + 2u*(size_t)nTwo;
  size_t uvIdxOff = facesOff + 3*nFaces + (size_t)(4*NG*NG)*2;
  int v[4];
  #pragma unroll
  for (int j = 0; j < 4; ++j) v[j] = idx[t*4+j];
  for (int k = 0; k < nt; ++k){
    size_t row = (nt == 1) ? (size_t)(oneI[t]-1u)
                           : (size_t)nOne + 2u*(size_t)(twoI[t]-1u) + (size_t)k;
    #pragma unroll
    for (int j = 0; j < 3; ++j){
      int e = c_tri[ti][k*3+j];
      int a = v[c_e0[e]], b = v[c_e1[e]];
      if (a > b){ int tmp = a; a = b; b = tmp; }
      uint32_t p = (a > 0) ? bincl[a-1] : 0u;
      while (skey[p] != (uint32_t)b) ++p;   // guaranteed present; avg ~8 probes, 1-2 lines
      out[facesOff + row*3 + j] = (float)(maskI[p] - 1u);
    }
    int tri = (nt == 2) ? k : 0;
    long long t4 = 4LL*t;
    out[uvIdxOff + row*3 + 0] = (float)t4;
    out[uvIdxOff + row*3 + 1] = (float)(t4 + tri + 1);
    out[uvIdxOff + row*3 + 2] = (float)(t4 + tri + 2);
  }
}

// fixed UV grid (numpy linspace float64 semantics, cast to f32)
__global__ void k_uvs(const uint32_t* __restrict__ maskI, const uint32_t* __restrict__ bincl,
                      const uint32_t* __restrict__ oneI, const uint32_t* __restrict__ twoI,
                      float* __restrict__ out){
  int r = blockIdx.x*blockDim.x + threadIdx.x;
  if (r >= 4*NG*NG) return;
  uint32_t nE      = (uint32_t)__builtin_amdgcn_readfirstlane((int)bincl[NVERT-1]);
  uint32_t nInterp = (uint32_t)__builtin_amdgcn_readfirstlane((int)maskI[nE-1]);
  uint32_t nOne    = (uint32_t)__builtin_amdgcn_readfirstlane((int)oneI[NTET-1]);
  uint32_t nTwo    = (uint32_t)__builtin_amdgcn_readfirstlane((int)twoI[NTET-1]);
  size_t uvOff = (size_t)3*nInterp + 3*((size_t)nOne + 2u*(size_t)nTwo);
  int cell = r >> 2, c = r & 3;
  int iy = cell / NG, jx = cell % NG;
  const double step = (1.0 - 1.0/NG)/(NG-1);
  float x = (jx == NG-1) ? (float)(1.0 - 1.0/NG) : (float)((double)jx*step);
  float y = (iy == NG-1) ? (float)(1.0 - 1.0/NG) : (float)((double)iy*step);
  float pad = (float)(0.9/NG);
  float u, vv;
  switch (c){
    case 0: u = x;                 vv = y;                 break;
    case 1: u = __fadd_rn(x, pad); vv = y;                 break;
    case 2: u = __fadd_rn(x, pad); vv = __fadd_rn(y, pad); break;
    default:u = x;                 vv = __fadd_rn(y, pad); break;
  }
  out[uvOff + (size_t)r*2 + 0] = u;
  out[uvOff + (size_t)r*2 + 1] = vv;
}

static void scan_u32(uint32_t* d, int L, uint32_t* part, hipStream_t s){
  int nb = (L + SCAN_EPB - 1)/SCAN_EPB;
  k_scan_block<<<nb, SCAN_T, 0, s>>>(d, part, L);
  if (nb > 1){
    k_scan_part<<<1, SCAN_T, 0, s>>>(part, nb);
    k_scan_add<<<nb, SCAN_T, 0, s>>>(d, part, L);
  }
}

extern "C" void kernel_launch(void* const* d_in, const int* in_sizes, int n_in,
                              void* d_out, int out_size, void* d_ws, size_t ws_size,
                              hipStream_t stream){
  const float* verts  = (const float*)d_in[0];
  const float* deform = (const float*)d_in[1];
  const float* ssign  = (const float*)d_in[2];
  const float* sabs   = (const float*)d_in[3];
  const int*   idx    = (const int*)d_in[4];
  float* out = (float*)d_out;

  char* ws = (char*)d_ws;
  size_t o = 0;
  auto alloc = [&](size_t bytes) -> void* {
    void* p = ws + o;
    o = (o + bytes + 255) & ~(size_t)255;
    return p;
  };
  float*    sdf     = (float*)   alloc(sizeof(float)*NVERT);
  uint8_t*  occ     = (uint8_t*) alloc(NVERT);
  uint8_t*  tetidx  = (uint8_t*) alloc(NTET);
  uint32_t* bincl   = (uint32_t*)alloc(sizeof(uint32_t)*NVERT);
  uint32_t* fill    = (uint32_t*)alloc(sizeof(uint32_t)*NVERT);
  uint32_t* oneI    = (uint32_t*)alloc(sizeof(uint32_t)*NTET);
  uint32_t* twoI    = (uint32_t*)alloc(sizeof(uint32_t)*NTET);
  uint32_t* maskI   = (uint32_t*)alloc(sizeof(uint32_t)*NE2);
  uint32_t* skey    = (uint32_t*)alloc(sizeof(uint32_t)*NE2);
  uint32_t* part    = (uint32_t*)alloc(sizeof(uint32_t)*2048);
  if (o > ws_size) return;  // workspace too small: bail loudly (validation fails)

  k_zero2<<<(NVERT+255)/256, 256, 0, stream>>>(bincl, fill, NVERT);

  k_sdf<<<(NVERT+255)/256, 256, 0, stream>>>(ssign, sabs, sdf, occ);
  k_tet<<<(NTET+255)/256, 256, 0, stream>>>(idx, occ, tetidx, oneI, twoI, bincl);

  scan_u32(bincl, NVERT, part, stream);

  k_scatter<<<(NTET+255)/256, 256, 0, stream>>>(idx, tetidx, bincl, fill, skey);
  k_bsort<<<1024, 256, 0, stream>>>(skey, bincl, maskI);

  scan_u32(maskI, NE2, part, stream);
  scan_u32(oneI, NTET, part, stream);
  scan_u32(twoI, NTET, part, stream);

  k_verts2<<<1024, 256, 0, stream>>>(skey, maskI, bincl, verts, deform, sdf, out);
  k_faces<<<(NTET+255)/256, 256, 0, stream>>>(idx, tetidx, oneI, twoI, maskI, bincl, skey, out);
  k_uvs<<<(4*NG*NG+255)/256, 256, 0, stream>>>(maskI, bincl, oneI, twoI, out);
}

// Round 5
// 652.135 us; speedup vs baseline: 1.4662x; 1.4662x over previous
//
#include <hip/hip_runtime.h>
#include <stdint.h>

#define NVERT 200000
#define NTET  1000000
#define NE2   3200000          // crossing-edge instance capacity (E[n]=3.0M, sigma~1.2k)
#define NG 1000
#define PAYB 23
#define PAYMASK ((1u<<PAYB)-1u)
#define KB 18
#define KMASK ((1u<<KB)-1u)

#define SCAN_T 256
#define SCAN_E 16
#define SCAN_EPB (SCAN_T*SCAN_E)   // 4096

__constant__ int c_tri[16][6] = {
  {-1,-1,-1,-1,-1,-1},{1,0,2,-1,-1,-1},{4,0,3,-1,-1,-1},{1,4,2,1,3,4},
  {3,1,5,-1,-1,-1},{2,3,0,2,5,3},{1,4,0,1,5,4},{4,2,5,-1,-1,-1},
  {4,5,2,-1,-1,-1},{4,1,0,4,5,1},{3,2,0,3,5,2},{1,3,5,-1,-1,-1},
  {4,1,2,4,3,1},{3,0,4,-1,-1,-1},{2,0,1,-1,-1,-1},{-1,-1,-1,-1,-1,-1}};
__constant__ int c_ntri[16] = {0,1,1,2,1,2,2,1,1,2,2,1,2,1,1,0};
__constant__ int c_e0[6] = {0,0,0,1,1,2};
__constant__ int c_e1[6] = {1,2,3,2,3,3};

__device__ __forceinline__ uint64_t shfl64(uint64_t x, int src){
  int lo = __shfl((int)(uint32_t)x, src, 64);
  int hi = __shfl((int)(uint32_t)(x >> 32), src, 64);
  return ((uint64_t)(uint32_t)hi << 32) | (uint32_t)lo;
}

// fused: sdf/occ compute + zero bincl/fill
__global__ void k_init(const float* __restrict__ ssign, const float* __restrict__ sabs,
                       float* __restrict__ sdf, uint8_t* __restrict__ occ,
                       uint32_t* __restrict__ bincl, uint32_t* __restrict__ fill){
  int i = blockIdx.x*blockDim.x + threadIdx.x;
  if (i >= NVERT) return;
  float s = ssign[i] * fabsf(sabs[i]);
  sdf[i] = s;
  occ[i] = (s > 0.0f) ? 1 : 0;
  bincl[i] = 0u;
  fill[i]  = 0u;
}

// per-tet: tetindex, packed one|two flags (u64), bucket counts for CROSSING edges
__global__ void k_tet(const int* __restrict__ idx, const uint8_t* __restrict__ occ,
                      uint8_t* __restrict__ tetidx, uint64_t* __restrict__ oneTwo,
                      uint32_t* __restrict__ bcnt){
  int t = blockIdx.x*blockDim.x + threadIdx.x;
  if (t >= NTET) return;
  int v[4];
  #pragma unroll
  for (int j = 0; j < 4; ++j) v[j] = idx[t*4+j];
  int ti = 0;
  #pragma unroll
  for (int j = 0; j < 4; ++j) ti |= (occ[v[j]] ? 1 : 0) << j;
  tetidx[t] = (uint8_t)ti;
  int nt = c_ntri[ti];
  oneTwo[t] = ((nt == 1) ? 1ull : 0ull) | (((nt == 2) ? 1ull : 0ull) << 32);
  if (nt == 0) return;
  #pragma unroll
  for (int e = 0; e < 6; ++e){
    int o0 = (ti >> c_e0[e]) & 1, o1 = (ti >> c_e1[e]) & 1;
    if (o0 == o1) continue;               // only crossing edges enter the pipeline
    int a = v[c_e0[e]], b = v[c_e1[e]];
    if (a > b){ int tmp = a; a = b; b = tmp; }
    atomicAdd((unsigned int*)&bcnt[a], 1u);
  }
}

// ---- in-place inclusive scan, u32 ----
__global__ void k_scan_block(uint32_t* __restrict__ d, uint32_t* __restrict__ part, int L){
  int tid = threadIdx.x;
  int base = blockIdx.x*SCAN_EPB + tid*SCAN_E;
  uint32_t v[SCAN_E];
  #pragma unroll
  for (int j = 0; j < SCAN_E; ++j){
    int i = base + j;
    v[j] = (i < L) ? d[i] : 0u;
  }
  #pragma unroll
  for (int j = 1; j < SCAN_E; ++j) v[j] += v[j-1];
  __shared__ uint32_t s[SCAN_T];
  s[tid] = v[SCAN_E-1];
  __syncthreads();
  for (int o = 1; o < SCAN_T; o <<= 1){
    uint32_t x = (tid >= o) ? s[tid-o] : 0u;
    __syncthreads();
    s[tid] += x;
    __syncthreads();
  }
  uint32_t off = s[tid] - v[SCAN_E-1];
  #pragma unroll
  for (int j = 0; j < SCAN_E; ++j){
    int i = base + j;
    if (i < L) d[i] = v[j] + off;
  }
  if (tid == SCAN_T-1 && part) part[blockIdx.x] = s[SCAN_T-1];
}

__global__ void k_scan_part(uint32_t* __restrict__ part, int n){
  int tid = threadIdx.x;
  int per = (n + SCAN_T - 1)/SCAN_T;
  int st = tid*per, en = st + per; if (en > n) en = n;
  uint32_t sum = 0;
  for (int i = st; i < en; ++i) sum += part[i];
  __shared__ uint32_t s[SCAN_T];
  s[tid] = sum;
  __syncthreads();
  for (int o = 1; o < SCAN_T; o <<= 1){
    uint32_t x = (tid >= o) ? s[tid-o] : 0u;
    __syncthreads();
    s[tid] += x;
    __syncthreads();
  }
  uint32_t off = s[tid] - sum;
  uint32_t run = off;
  for (int i = st; i < en; ++i){ run += part[i]; part[i] = run; }
}

__global__ void k_scan_add(uint32_t* __restrict__ d, const uint32_t* __restrict__ part, int L){
  int blk = blockIdx.x;
  if (blk == 0) return;
  uint32_t off = part[blk-1];
  int base = blk*SCAN_EPB;
  #pragma unroll
  for (int j = 0; j < SCAN_E; ++j){
    int i = base + j*SCAN_T + threadIdx.x;
    if (i < L) d[i] += off;
  }
}

// ---- in-place inclusive scan, u64 (two independent 32-bit fields, no cross-carry) ----
__global__ void k_scan_block64(uint64_t* __restrict__ d, uint64_t* __restrict__ part, int L){
  int tid = threadIdx.x;
  int base = blockIdx.x*SCAN_EPB + tid*SCAN_E;
  uint64_t v[SCAN_E];
  #pragma unroll
  for (int j = 0; j < SCAN_E; ++j){
    int i = base + j;
    v[j] = (i < L) ? d[i] : 0ull;
  }
  #pragma unroll
  for (int j = 1; j < SCAN_E; ++j) v[j] += v[j-1];
  __shared__ uint64_t s[SCAN_T];
  s[tid] = v[SCAN_E-1];
  __syncthreads();
  for (int o = 1; o < SCAN_T; o <<= 1){
    uint64_t x = (tid >= o) ? s[tid-o] : 0ull;
    __syncthreads();
    s[tid] += x;
    __syncthreads();
  }
  uint64_t off = s[tid] - v[SCAN_E-1];
  #pragma unroll
  for (int j = 0; j < SCAN_E; ++j){
    int i = base + j;
    if (i < L) d[i] = v[j] + off;
  }
  if (tid == SCAN_T-1 && part) part[blockIdx.x] = s[SCAN_T-1];
}

__global__ void k_scan_part64(uint64_t* __restrict__ part, int n){
  int tid = threadIdx.x;
  int per = (n + SCAN_T - 1)/SCAN_T;
  int st = tid*per, en = st + per; if (en > n) en = n;
  uint64_t sum = 0;
  for (int i = st; i < en; ++i) sum += part[i];
  __shared__ uint64_t s[SCAN_T];
  s[tid] = sum;
  __syncthreads();
  for (int o = 1; o < SCAN_T; o <<= 1){
    uint64_t x = (tid >= o) ? s[tid-o] : 0ull;
    __syncthreads();
    s[tid] += x;
    __syncthreads();
  }
  uint64_t off = s[tid] - sum;
  uint64_t run = off;
  for (int i = st; i < en; ++i){ run += part[i]; part[i] = run; }
}

__global__ void k_scan_add64(uint64_t* __restrict__ d, const uint64_t* __restrict__ part, int L){
  int blk = blockIdx.x;
  if (blk == 0) return;
  uint64_t off = part[blk-1];
  int base = blk*SCAN_EPB;
  #pragma unroll
  for (int j = 0; j < SCAN_E; ++j){
    int i = base + j*SCAN_T + threadIdx.x;
    if (i < L) d[i] += off;
  }
}

// scatter crossing-edge keys (a|b|payload) into per-min-vertex buckets
__global__ void k_scatter(const int* __restrict__ idx, const uint8_t* __restrict__ tetidx,
                          const uint32_t* __restrict__ bincl, uint32_t* __restrict__ fill,
                          uint64_t* __restrict__ skey){
  int t = blockIdx.x*blockDim.x + threadIdx.x;
  if (t >= NTET) return;
  int ti = tetidx[t];
  if (c_ntri[ti] == 0) return;
  int v[4];
  #pragma unroll
  for (int j = 0; j < 4; ++j) v[j] = idx[t*4+j];
  #pragma unroll
  for (int e = 0; e < 6; ++e){
    int o0 = (ti >> c_e0[e]) & 1, o1 = (ti >> c_e1[e]) & 1;
    if (o0 == o1) continue;
    int a = v[c_e0[e]], b = v[c_e1[e]];
    if (a > b){ int tmp = a; a = b; b = tmp; }
    uint32_t base = (a > 0) ? bincl[a-1] : 0u;
    uint32_t p = base + atomicAdd((unsigned int*)&fill[a], 1u);
    if (p < NE2)
      skey[p] = ((uint64_t)(uint32_t)a << (PAYB+KB)) | ((uint64_t)(uint32_t)b << PAYB)
              | (uint32_t)(t*6 + e);
  }
}

// persistent-wave per-bucket rank sort (keys distinct via payload -> strict ranks),
// fused head-flag output into maskA (pre-scan flags).
__global__ void k_bsort(uint64_t* __restrict__ skey, const uint32_t* __restrict__ bincl,
                        uint32_t* __restrict__ maskA){
  int gid  = blockIdx.x*blockDim.x + threadIdx.x;
  int w    = gid >> 6;
  int lane = threadIdx.x & 63;
  int W    = (gridDim.x*blockDim.x) >> 6;
  for (int b = w; b < NVERT; b += W){
    uint32_t s0 = (b > 0) ? bincl[b-1] : 0u;
    uint32_t e0 = bincl[b];
    int n = (int)(e0 - s0);
    if (n <= 0) continue;
    if (n == 1){
      if (lane == 0) maskA[s0] = 1u;
      continue;
    }
    if (n <= 64){
      uint64_t ki = (lane < n) ? skey[s0+lane] : ~0ull;
      int r = 0; bool dup = false;
      for (int j = 0; j < n; ++j){
        uint64_t kj = shfl64(ki, j);
        bool lt = (kj < ki);
        r += lt ? 1 : 0;
        dup |= lt && ((kj >> PAYB) == (ki >> PAYB));
      }
      if (lane < n){
        skey[s0 + r] = ki;
        maskA[s0 + r] = dup ? 0u : 1u;
      }
    } else if (n <= 128){
      int n2 = n - 64;
      uint64_t k0 = skey[s0+lane];                                // first 64 all valid
      uint64_t k1 = (lane < n2) ? skey[s0+64+lane] : ~0ull;
      int r0 = 0, r1 = 0; bool d0 = false, d1 = false;
      for (int j = 0; j < 64; ++j){
        uint64_t kj = shfl64(k0, j);
        bool lt0 = (kj < k0);
        r0 += lt0 ? 1 : 0;  d0 |= lt0 && ((kj >> PAYB) == (k0 >> PAYB));
        bool lt1 = (kj < k1);
        r1 += lt1 ? 1 : 0;  d1 |= lt1 && ((kj >> PAYB) == (k1 >> PAYB));
      }
      for (int j = 0; j < n2; ++j){
        uint64_t kj = shfl64(k1, j);
        bool lt0 = (kj < k0);
        r0 += lt0 ? 1 : 0;  d0 |= lt0 && ((kj >> PAYB) == (k0 >> PAYB));
        bool lt1 = (kj < k1);
        r1 += lt1 ? 1 : 0;  d1 |= lt1 && ((kj >> PAYB) == (k1 >> PAYB));
      }
      { skey[s0 + r0] = k0; maskA[s0 + r0] = d0 ? 0u : 1u; }
      if (lane < n2){ skey[s0 + r1] = k1; maskA[s0 + r1] = d1 ? 0u : 1u; }
    } else if (lane == 0){
      // pathological fallback (never expected at seed 0)
      for (int i = 1; i < n; ++i){
        uint64_t x = skey[s0+i];
        int j = i-1;
        while (j >= 0 && skey[s0+j] > x){ skey[s0+j+1] = skey[s0+j]; --j; }
        skey[s0+j+1] = x;
      }
      maskA[s0] = 1u;
      for (int i = 1; i < n; ++i)
        maskA[s0+i] = ((skey[s0+i] >> PAYB) != (skey[s0+i-1] >> PAYB)) ? 1u : 0u;
    }
  }
}

// per-instance: e2v[payload] = vertex rank; heads interpolate + write out_verts
__global__ void k_emit(const uint64_t* __restrict__ skey, const uint32_t* __restrict__ maskI,
                       const uint32_t* __restrict__ bincl,
                       const float* __restrict__ verts, const float* __restrict__ deform,
                       const float* __restrict__ sdf,
                       uint32_t* __restrict__ edge2vert, float* __restrict__ out){
  int i = blockIdx.x*blockDim.x + threadIdx.x;
  if (i >= NE2) return;
  uint32_t nE = (uint32_t)__builtin_amdgcn_readfirstlane((int)bincl[NVERT-1]);
  if ((uint32_t)i >= nE) return;
  uint64_t k = skey[i];
  uint32_t m = maskI[i];
  uint32_t pm = (i > 0) ? maskI[i-1] : 0u;
  uint32_t vid = m - 1u;
  edge2vert[(uint32_t)(k & PAYMASK)] = vid;
  if (m == pm) return;                      // duplicate instance
  int a = (int)(k >> (PAYB+KB)), b = (int)((k >> PAYB) & KMASK);
  float sa = sdf[a], sb = sdf[b];
  float denom = sa - sb;
  float w0 = __fdiv_rn(-sb, denom);
  float w1 = __fdiv_rn(sa, denom);
  #pragma unroll
  for (int c = 0; c < 3; ++c){
    float pa = __fadd_rn(verts[a*3+c], __fmul_rn(0.0078125f, deform[a*3+c]));
    float pb = __fadd_rn(verts[b*3+c], __fmul_rn(0.0078125f, deform[b*3+c]));
    out[(size_t)vid*3 + c] = __fadd_rn(__fmul_rn(pa, w0), __fmul_rn(pb, w1));
  }
}

// faces + uv_idx via coalesced edge2vert lookup
__global__ void k_faces(const uint8_t* __restrict__ tetidx,
                        const uint64_t* __restrict__ oneTwoI,
                        const uint32_t* __restrict__ maskI, const uint32_t* __restrict__ bincl,
                        const uint32_t* __restrict__ edge2vert, float* __restrict__ out){
  int t = blockIdx.x*blockDim.x + threadIdx.x;
  if (t >= NTET) return;
  int ti = tetidx[t];
  int nt = c_ntri[ti];
  if (nt == 0) return;
  uint32_t nE      = (uint32_t)__builtin_amdgcn_readfirstlane((int)bincl[NVERT-1]);
  uint32_t nInterp = (uint32_t)__builtin_amdgcn_readfirstlane((int)maskI[nE-1]);
  uint64_t totOT   = oneTwoI[NTET-1];
  uint32_t nOne    = (uint32_t)__builtin_amdgcn_readfirstlane((int)(uint32_t)totOT);
  uint32_t nTwo    = (uint32_t)__builtin_amdgcn_readfirstlane((int)(uint32_t)(totOT >> 32));
  size_t facesOff = (size_t)3*nInterp;
  size_t nFaces = (size_t)nOne + 2u*(size_t)nTwo;
  size_t uvIdxOff = facesOff + 3*nFaces + (size_t)(4*NG*NG)*2;
  uint64_t ot = oneTwoI[t];
  uint32_t oneR = (uint32_t)ot, twoR = (uint32_t)(ot >> 32);
  for (int k = 0; k < nt; ++k){
    size_t row = (nt == 1) ? (size_t)(oneR-1u)
                           : (size_t)nOne + 2u*(size_t)(twoR-1u) + (size_t)k;
    #pragma unroll
    for (int j = 0; j < 3; ++j){
      int e = c_tri[ti][k*3+j];
      out[facesOff + row*3 + j] = (float)edge2vert[t*6 + e];
    }
    int tri = (nt == 2) ? k : 0;
    long long t4 = 4LL*t;
    out[uvIdxOff + row*3 + 0] = (float)t4;
    out[uvIdxOff + row*3 + 1] = (float)(t4 + tri + 1);
    out[uvIdxOff + row*3 + 2] = (float)(t4 + tri + 2);
  }
}

// fixed UV grid (numpy linspace float64 semantics, cast to f32)
__global__ void k_uvs(const uint32_t* __restrict__ maskI, const uint32_t* __restrict__ bincl,
                      const uint64_t* __restrict__ oneTwoI, float* __restrict__ out){
  int r = blockIdx.x*blockDim.x + threadIdx.x;
  if (r >= 4*NG*NG) return;
  uint32_t nE      = (uint32_t)__builtin_amdgcn_readfirstlane((int)bincl[NVERT-1]);
  uint32_t nInterp = (uint32_t)__builtin_amdgcn_readfirstlane((int)maskI[nE-1]);
  uint64_t totOT   = oneTwoI[NTET-1];
  uint32_t nOne    = (uint32_t)__builtin_amdgcn_readfirstlane((int)(uint32_t)totOT);
  uint32_t nTwo    = (uint32_t)__builtin_amdgcn_readfirstlane((int)(uint32_t)(totOT >> 32));
  size_t uvOff = (size_t)3*nInterp + 3*((size_t)nOne + 2u*(size_t)nTwo);
  int cell = r >> 2, c = r & 3;
  int iy = cell / NG, jx = cell % NG;
  const double step = (1.0 - 1.0/NG)/(NG-1);
  float x = (jx == NG-1) ? (float)(1.0 - 1.0/NG) : (float)((double)jx*step);
  float y = (iy == NG-1) ? (float)(1.0 - 1.0/NG) : (float)((double)iy*step);
  float pad = (float)(0.9/NG);
  float u, vv;
  switch (c){
    case 0: u = x;                 vv = y;                 break;
    case 1: u = __fadd_rn(x, pad); vv = y;                 break;
    case 2: u = __fadd_rn(x, pad); vv = __fadd_rn(y, pad); break;
    default:u = x;                 vv = __fadd_rn(y, pad); break;
  }
  out[uvOff + (size_t)r*2 + 0] = u;
  out[uvOff + (size_t)r*2 + 1] = vv;
}

static void scan_u32(uint32_t* d, int L, uint32_t* part, hipStream_t s){
  int nb = (L + SCAN_EPB - 1)/SCAN_EPB;
  k_scan_block<<<nb, SCAN_T, 0, s>>>(d, part, L);
  if (nb > 1){
    k_scan_part<<<1, SCAN_T, 0, s>>>(part, nb);
    k_scan_add<<<nb, SCAN_T, 0, s>>>(d, part, L);
  }
}

static void scan_u64(uint64_t* d, int L, uint64_t* part, hipStream_t s){
  int nb = (L + SCAN_EPB - 1)/SCAN_EPB;
  k_scan_block64<<<nb, SCAN_T, 0, s>>>(d, part, L);
  if (nb > 1){
    k_scan_part64<<<1, SCAN_T, 0, s>>>(part, nb);
    k_scan_add64<<<nb, SCAN_T, 0, s>>>(d, part, L);
  }
}

extern "C" void kernel_launch(void* const* d_in, const int* in_sizes, int n_in,
                              void* d_out, int out_size, void* d_ws, size_t ws_size,
                              hipStream_t stream){
  const float* verts  = (const float*)d_in[0];
  const float* deform = (const float*)d_in[1];
  const float* ssign  = (const float*)d_in[2];
  const float* sabs   = (const float*)d_in[3];
  const int*   idx    = (const int*)d_in[4];
  float* out = (float*)d_out;

  char* ws = (char*)d_ws;
  size_t o = 0;
  auto alloc = [&](size_t bytes) -> void* {
    void* p = ws + o;
    o = (o + bytes + 255) & ~(size_t)255;
    return p;
  };
  float*    sdf     = (float*)   alloc(sizeof(float)*NVERT);
  uint8_t*  occ     = (uint8_t*) alloc(NVERT);
  uint8_t*  tetidx  = (uint8_t*) alloc(NTET);
  uint32_t* bincl   = (uint32_t*)alloc(sizeof(uint32_t)*NVERT);
  uint32_t* fill    = (uint32_t*)alloc(sizeof(uint32_t)*NVERT);
  uint64_t* oneTwo  = (uint64_t*)alloc(sizeof(uint64_t)*NTET);
  uint32_t* maskI   = (uint32_t*)alloc(sizeof(uint32_t)*NE2);
  uint64_t* skey    = (uint64_t*)alloc(sizeof(uint64_t)*NE2);
  uint32_t* e2v     = (uint32_t*)alloc(sizeof(uint32_t)*NTET*6);
  uint32_t* part    = (uint32_t*)alloc(sizeof(uint32_t)*2048);
  uint64_t* part64  = (uint64_t*)alloc(sizeof(uint64_t)*2048);
  if (o > ws_size) return;  // workspace too small: bail loudly (validation fails)

  k_init<<<(NVERT+255)/256, 256, 0, stream>>>(ssign, sabs, sdf, occ, bincl, fill);
  k_tet<<<(NTET+255)/256, 256, 0, stream>>>(idx, occ, tetidx, oneTwo, bincl);

  scan_u32(bincl, NVERT, part, stream);

  k_scatter<<<(NTET+255)/256, 256, 0, stream>>>(idx, tetidx, bincl, fill, skey);
  k_bsort<<<1024, 256, 0, stream>>>(skey, bincl, maskI);

  scan_u32(maskI, NE2, part, stream);
  scan_u64(oneTwo, NTET, part64, stream);

  k_emit<<<(NE2+255)/256, 256, 0, stream>>>(skey, maskI, bincl, verts, deform, sdf, e2v, out);
  k_faces<<<(NTET+255)/256, 256, 0, stream>>>(tetidx, oneTwo, maskI, bincl, e2v, out);
  k_uvs<<<(4*NG*NG+255)/256, 256, 0, stream>>>(maskI, bincl, oneTwo, out);
}